// Round 2
// baseline (849.155 us; speedup 1.0000x reference)
//
#include <hip/hip_runtime.h>
#include <hip/hip_bf16.h>

// DeformableAttention3D — MI355X (gfx950)
#define EMBED    256
#define HEADS    8
#define LEVELS   4
#define POINTS   4
#define BATCH    2
#define M_TOT    21760   // 128*128 + 64*64 + 32*32 + 16*16

typedef __hip_bfloat16 bf16;

__device__ __constant__ int c_H[LEVELS]  = {128, 64, 32, 16};
__device__ __constant__ int c_St[LEVELS] = {0, 16384, 20480, 21504};

// Dtype-polymorphic load: BF=true -> buffer holds bf16, else f32.
template<bool BF>
__device__ __forceinline__ float ldf(const void* p, size_t i) {
  if (BF) return __bfloat162float(((const bf16*)p)[i]);
  else    return ((const float*)p)[i];
}

__device__ __forceinline__ float vt2f(float x) { return x; }
__device__ __forceinline__ float vt2f(bf16 x)  { return __bfloat162float(x); }
__device__ __forceinline__ void  f2vt(float* d, float x) { *d = x; }
__device__ __forceinline__ void  f2vt(bf16* d,  float x) { *d = __float2bfloat16(x); }

// ---------------------------------------------------------------------------
// Detector: if query were f32 misread as bf16, ~1/256 of uint16 halves decode
// as bf16 Inf/NaN (exponent field all ones). bf16 normal data has none.
// flag = 1 -> buffers are bf16 ; flag = 0 -> buffers are f32.
// ---------------------------------------------------------------------------
__global__ __launch_bounds__(256)
void k_detect(const unsigned short* __restrict__ q16, int* __restrict__ flag) {
  __shared__ int cnt;
  if (threadIdx.x == 0) cnt = 0;
  __syncthreads();
  int c = 0;
  for (int i = threadIdx.x; i < 8192; i += 256) {
    unsigned short v = q16[i];
    if ((v & 0x7F80u) == 0x7F80u) ++c;   // bf16 Inf/NaN pattern
  }
  if (c) atomicAdd(&cnt, c);
  __syncthreads();
  if (threadIdx.x == 0) flag[0] = (cnt == 0) ? 1 : 0;
}

// ---------------------------------------------------------------------------
// v = value @ W_v + b_v   (one block per row m, 256 threads = cols)
// ---------------------------------------------------------------------------
template<bool BF, class VT>
__device__ void vproj_body(const void* __restrict__ value,
                           const void* __restrict__ W_v,
                           const void* __restrict__ b_v,
                           VT* __restrict__ v, int BM) {
  int m = blockIdx.x;
  if (m >= BM) return;
  int t = threadIdx.x;
  __shared__ float row[EMBED];
  row[t] = ldf<BF>(value, (size_t)m * EMBED + t);
  __syncthreads();
  float acc = ldf<BF>(b_v, t);
#pragma unroll 8
  for (int e = 0; e < EMBED; ++e)
    acc = fmaf(row[e], ldf<BF>(W_v, (size_t)e * EMBED + t), acc);
  f2vt(&v[(size_t)m * EMBED + t], acc);
}

template<class VT>
__global__ __launch_bounds__(256)
void k_value_proj(const void* value, const void* W_v, const void* b_v,
                  VT* v, int BM, const int* flag) {
  if (*flag) vproj_body<true,  VT>(value, W_v, b_v, v, BM);
  else       vproj_body<false, VT>(value, W_v, b_v, v, BM);
}

// ---------------------------------------------------------------------------
// Fused: offsets GEMV + attn GEMV + softmax + bilinear sampling.
// One block per query q = b*N + n, 256 threads, t = h*32 + d.
// ---------------------------------------------------------------------------
template<bool BF, class VT>
__device__ void fused_body(const void* __restrict__ query,
                           const void* __restrict__ ref_points,
                           const void* __restrict__ W_off,
                           const void* __restrict__ b_off,
                           const void* __restrict__ W_attn,
                           const void* __restrict__ b_attn,
                           const VT* __restrict__ v,
                           void* __restrict__ out, int N, int BN) {
  int q = blockIdx.x;
  if (q >= BN) return;
  int b = q / N;
  int t = threadIdx.x;

  __shared__ float row[EMBED];
  __shared__ float s_off[EMBED];
  __shared__ float s_aw[HEADS * LEVELS * POINTS];  // logits, then weights
  __shared__ float s_rp[2];

  row[t] = ldf<BF>(query, (size_t)q * EMBED + t);
  if (t < 2) s_rp[t] = ldf<BF>(ref_points, (size_t)q * 2 + t);
  __syncthreads();

  // offsets column t
  {
    float acc = ldf<BF>(b_off, t);
#pragma unroll 8
    for (int e = 0; e < EMBED; ++e)
      acc = fmaf(row[e], ldf<BF>(W_off, (size_t)e * EMBED + t), acc);
    s_off[t] = acc;
  }
  // attention logits column t (t < 128)
  if (t < 128) {
    float acc = ldf<BF>(b_attn, t);
#pragma unroll 8
    for (int e = 0; e < EMBED; ++e)
      acc = fmaf(row[e], ldf<BF>(W_attn, (size_t)e * 128 + t), acc);
    s_aw[t] = acc;
  }
  __syncthreads();

  // per-head softmax over 16 (level,point) entries
  float aval = 0.f;
  if (t < 128) {
    int base = t & ~15;
    float mx = -1e30f;
#pragma unroll
    for (int i = 0; i < 16; ++i) mx = fmaxf(mx, s_aw[base + i]);
    float sum = 0.f;
#pragma unroll
    for (int i = 0; i < 16; ++i) sum += expf(s_aw[base + i] - mx);
    aval = expf(s_aw[t] - mx) / sum;
  }
  __syncthreads();
  if (t < 128) s_aw[t] = aval;
  __syncthreads();

  // bilinear sampling
  int h = t >> 5;
  const VT* vb = v + (size_t)b * M_TOT * EMBED;
  float o = 0.f;
#pragma unroll
  for (int l = 0; l < LEVELS; ++l) {
    const int Hl = c_H[l], Wl = c_H[l];
    const VT* vl = vb + (size_t)c_St[l] * EMBED;
    const float fW = (float)Wl, fH = (float)Hl;
#pragma unroll
    for (int p = 0; p < POINTS; ++p) {
      int oi = ((h * LEVELS + l) * POINTS + p) << 1;
      float x = (s_rp[0] + s_off[oi]     / fW) * fW - 0.5f;
      float y = (s_rp[1] + s_off[oi + 1] / fH) * fH - 0.5f;
      float x0f = floorf(x), y0f = floorf(y);
      float lx = x - x0f, ly = y - y0f;
      int x0 = (int)x0f, y0 = (int)y0f;
      float wa = s_aw[(h * LEVELS + l) * POINTS + p];
      float cw[4] = {(1.f - lx) * (1.f - ly), lx * (1.f - ly),
                     (1.f - lx) * ly,         lx * ly};
      const int dxs[4] = {0, 1, 0, 1};
      const int dys[4] = {0, 0, 1, 1};
#pragma unroll
      for (int cidx = 0; cidx < 4; ++cidx) {
        int xi = x0 + dxs[cidx];
        int yi = y0 + dys[cidx];
        bool valid = (xi >= 0) & (xi < Wl) & (yi >= 0) & (yi < Hl);
        int xc = min(max(xi, 0), Wl - 1);
        int yc = min(max(yi, 0), Hl - 1);
        float g = vt2f(vl[(size_t)(yc * Wl + xc) * EMBED + t]);
        o += (valid ? wa * cw[cidx] : 0.f) * g;
      }
    }
  }
  if (BF) ((bf16*)out)[(size_t)q * EMBED + t] = __float2bfloat16(o);
  else    ((float*)out)[(size_t)q * EMBED + t] = o;
}

template<class VT>
__global__ __launch_bounds__(256)
void k_fused(const void* query, const void* ref_points,
             const void* W_off, const void* b_off,
             const void* W_attn, const void* b_attn,
             const VT* v, void* out, int N, int BN, const int* flag) {
  if (*flag) fused_body<true,  VT>(query, ref_points, W_off, b_off, W_attn, b_attn, v, out, N, BN);
  else       fused_body<false, VT>(query, ref_points, W_off, b_off, W_attn, b_attn, v, out, N, BN);
}

// ---------------------------------------------------------------------------
extern "C" void kernel_launch(void* const* d_in, const int* in_sizes, int n_in,
                              void* d_out, int out_size, void* d_ws, size_t ws_size,
                              hipStream_t stream) {
  const void* query      = d_in[0];
  // d_in[1] = key : unused by the reference
  const void* value      = d_in[2];
  const void* ref_points = d_in[3];
  // d_in[4] spatial_shapes (int32), d_in[5] level_start_idx (int32): constants
  const void* W_off  = d_in[6];
  const void* b_off  = d_in[7];
  const void* W_attn = d_in[8];
  const void* b_attn = d_in[9];
  const void* W_v    = d_in[10];
  const void* b_v    = d_in[11];

  const int BN = in_sizes[0] / EMBED;   // B*N = 20000
  const int BM = in_sizes[2] / EMBED;   // B*M = 43520
  const int N  = BN / BATCH;            // 10000

  int*  flag    = (int*)d_ws;
  char* ws_base = (char*)d_ws + 256;

  k_detect<<<1, 256, 0, stream>>>((const unsigned short*)query, flag);

  const size_t need_f32 = 256 + (size_t)BM * EMBED * sizeof(float);
  if (ws_size >= need_f32) {
    float* ws_v = (float*)ws_base;
    k_value_proj<float><<<BM, 256, 0, stream>>>(value, W_v, b_v, ws_v, BM, flag);
    k_fused<float><<<BN, 256, 0, stream>>>(query, ref_points, W_off, b_off,
                                           W_attn, b_attn, ws_v, d_out, N, BN, flag);
  } else {
    bf16* ws_v = (bf16*)ws_base;
    k_value_proj<bf16><<<BM, 256, 0, stream>>>(value, W_v, b_v, ws_v, BM, flag);
    k_fused<bf16><<<BN, 256, 0, stream>>>(query, ref_points, W_off, b_off,
                                          W_attn, b_attn, ws_v, d_out, N, BN, flag);
  }
}

// Round 6
// 615.876 us; speedup vs baseline: 1.3788x; 1.3788x over previous
//
#include <hip/hip_runtime.h>
#include <hip/hip_bf16.h>

// DeformableAttention3D — MI355X (gfx950)
// R6 = R2's passing source with ONE change: k_value_proj -> k_vgemv8.
#define EMBED    256
#define HEADS    8
#define LEVELS   4
#define POINTS   4
#define BATCH    2
#define M_TOT    21760   // 128*128 + 64*64 + 32*32 + 16*16

typedef __hip_bfloat16 bf16;
typedef __attribute__((ext_vector_type(8))) short short8;

__device__ __constant__ int c_H[LEVELS]  = {128, 64, 32, 16};
__device__ __constant__ int c_St[LEVELS] = {0, 16384, 20480, 21504};

template<bool BF>
__device__ __forceinline__ float ldf(const void* p, size_t i) {
  if (BF) return __bfloat162float(((const bf16*)p)[i]);
  else    return ((const float*)p)[i];
}
__device__ __forceinline__ float vt2f(float x) { return x; }
__device__ __forceinline__ float vt2f(bf16 x)  { return __bfloat162float(x); }

// ---------------------------------------------------------------------------
// Dtype detector (flag=1 -> buffers bf16, flag=0 -> f32). Verbatim R2.
// ---------------------------------------------------------------------------
__global__ __launch_bounds__(256)
void k_detect(const unsigned short* __restrict__ q16, int* __restrict__ flag) {
  __shared__ int cnt;
  if (threadIdx.x == 0) cnt = 0;
  __syncthreads();
  int c = 0;
  for (int i = threadIdx.x; i < 8192; i += 256) {
    unsigned short v = q16[i];
    if ((v & 0x7F80u) == 0x7F80u) ++c;   // bf16 Inf/NaN pattern
  }
  if (c) atomicAdd(&cnt, c);
  __syncthreads();
  if (threadIdx.x == 0) flag[0] = (cnt == 0) ? 1 : 0;
}

// ---------------------------------------------------------------------------
// THE ONE CHANGE UNDER TEST: 8-rows-per-block LDS-staged GEMV for v.
// v[M x 256] = value[M x 256] @ W_v[256 x 256] + b_v, f32 out.
// ---------------------------------------------------------------------------
template<bool BF>
__device__ void vgemv8_body(const void* __restrict__ A, const void* __restrict__ W,
                            const void* __restrict__ bias, float* __restrict__ C,
                            int M) {
  const int t  = threadIdx.x;            // 256 threads
  const int r0 = blockIdx.x * 8;
  if (r0 >= M) return;

  __shared__ float rowA[8][EMBED];
  {
    int r  = t >> 5;                     // 0..7
    int rr = min(r0 + r, M - 1);         // clamp reads; stores guarded
    int c0 = (t & 31) * 8;               // 0..248
    if (BF) {
      const bf16* ap = (const bf16*)A + (size_t)rr * EMBED + c0;
      short8 a = *(const short8*)ap;
#pragma unroll
      for (int j = 0; j < 8; ++j) {
        short s = a[j];
        bf16 hb = *reinterpret_cast<bf16*>(&s);
        rowA[r][c0 + j] = __bfloat162float(hb);
      }
    } else {
      const float* ap = (const float*)A + (size_t)rr * EMBED + c0;
#pragma unroll
      for (int j = 0; j < 8; ++j) rowA[r][c0 + j] = ap[j];
    }
  }
  __syncthreads();

  const int n = t;                        // column, N = 256 fixed
  const float b = ldf<BF>(bias, n);
  float acc[8];
#pragma unroll
  for (int r = 0; r < 8; ++r) acc[r] = b;
#pragma unroll 4
  for (int k = 0; k < EMBED; ++k) {
    float w = ldf<BF>(W, (size_t)k * EMBED + n);
#pragma unroll
    for (int r = 0; r < 8; ++r) acc[r] = fmaf(rowA[r][k], w, acc[r]);
  }
#pragma unroll
  for (int r = 0; r < 8; ++r)
    if (r0 + r < M) C[(size_t)(r0 + r) * EMBED + n] = acc[r];
}

__global__ __launch_bounds__(256)
void k_vgemv8(const void* A, const void* W, const void* bias, float* C,
              int M, const int* flag) {
  if (*flag) vgemv8_body<true >(A, W, bias, C, M);
  else       vgemv8_body<false>(A, W, bias, C, M);
}

// ---------------------------------------------------------------------------
// VERBATIM R2: fused offsets-GEMV + attn-GEMV + softmax + sampling.
// ---------------------------------------------------------------------------
template<bool BF, class VT>
__device__ void fused_body(const void* __restrict__ query,
                           const void* __restrict__ ref_points,
                           const void* __restrict__ W_off,
                           const void* __restrict__ b_off,
                           const void* __restrict__ W_attn,
                           const void* __restrict__ b_attn,
                           const VT* __restrict__ v,
                           void* __restrict__ out, int N, int BN) {
  int q = blockIdx.x;
  if (q >= BN) return;
  int b = q / N;
  int t = threadIdx.x;

  __shared__ float row[EMBED];
  __shared__ float s_off[EMBED];
  __shared__ float s_aw[HEADS * LEVELS * POINTS];
  __shared__ float s_rp[2];

  row[t] = ldf<BF>(query, (size_t)q * EMBED + t);
  if (t < 2) s_rp[t] = ldf<BF>(ref_points, (size_t)q * 2 + t);
  __syncthreads();

  {
    float acc = ldf<BF>(b_off, t);
#pragma unroll 8
    for (int e = 0; e < EMBED; ++e)
      acc = fmaf(row[e], ldf<BF>(W_off, (size_t)e * EMBED + t), acc);
    s_off[t] = acc;
  }
  if (t < 128) {
    float acc = ldf<BF>(b_attn, t);
#pragma unroll 8
    for (int e = 0; e < EMBED; ++e)
      acc = fmaf(row[e], ldf<BF>(W_attn, (size_t)e * 128 + t), acc);
    s_aw[t] = acc;
  }
  __syncthreads();

  float aval = 0.f;
  if (t < 128) {
    int base = t & ~15;
    float mx = -1e30f;
#pragma unroll
    for (int i = 0; i < 16; ++i) mx = fmaxf(mx, s_aw[base + i]);
    float sum = 0.f;
#pragma unroll
    for (int i = 0; i < 16; ++i) sum += expf(s_aw[base + i] - mx);
    aval = expf(s_aw[t] - mx) / sum;
  }
  __syncthreads();
  if (t < 128) s_aw[t] = aval;
  __syncthreads();

  int h = t >> 5;
  const VT* vb = v + (size_t)b * M_TOT * EMBED;
  float o = 0.f;
#pragma unroll
  for (int l = 0; l < LEVELS; ++l) {
    const int Hl = c_H[l], Wl = c_H[l];
    const VT* vl = vb + (size_t)c_St[l] * EMBED;
    const float fW = (float)Wl, fH = (float)Hl;
#pragma unroll
    for (int p = 0; p < POINTS; ++p) {
      int oi = ((h * LEVELS + l) * POINTS + p) << 1;
      float x = (s_rp[0] + s_off[oi]     / fW) * fW - 0.5f;
      float y = (s_rp[1] + s_off[oi + 1] / fH) * fH - 0.5f;
      float x0f = floorf(x), y0f = floorf(y);
      float lx = x - x0f, ly = y - y0f;
      int x0 = (int)x0f, y0 = (int)y0f;
      float wa = s_aw[(h * LEVELS + l) * POINTS + p];
      float cw[4] = {(1.f - lx) * (1.f - ly), lx * (1.f - ly),
                     (1.f - lx) * ly,         lx * ly};
      const int dxs[4] = {0, 1, 0, 1};
      const int dys[4] = {0, 0, 1, 1};
#pragma unroll
      for (int cidx = 0; cidx < 4; ++cidx) {
        int xi = x0 + dxs[cidx];
        int yi = y0 + dys[cidx];
        bool valid = (xi >= 0) & (xi < Wl) & (yi >= 0) & (yi < Hl);
        int xc = min(max(xi, 0), Wl - 1);
        int yc = min(max(yi, 0), Hl - 1);
        float g = vt2f(vl[(size_t)(yc * Wl + xc) * EMBED + t]);
        o += (valid ? wa * cw[cidx] : 0.f) * g;
      }
    }
  }
  if (BF) ((bf16*)out)[(size_t)q * EMBED + t] = __float2bfloat16(o);
  else    ((float*)out)[(size_t)q * EMBED + t] = o;
}

template<class VT>
__global__ __launch_bounds__(256)
void k_fused(const void* query, const void* ref_points,
             const void* W_off, const void* b_off,
             const void* W_attn, const void* b_attn,
             const VT* v, void* out, int N, int BN, const int* flag) {
  if (*flag) fused_body<true,  VT>(query, ref_points, W_off, b_off, W_attn, b_attn, v, out, N, BN);
  else       fused_body<false, VT>(query, ref_points, W_off, b_off, W_attn, b_attn, v, out, N, BN);
}

// ---------------------------------------------------------------------------
// VERBATIM R2: value projection (fallback path only).
// ---------------------------------------------------------------------------
template<bool BF, class VT>
__device__ void vproj_body(const void* __restrict__ value,
                           const void* __restrict__ W_v,
                           const void* __restrict__ b_v,
                           VT* __restrict__ v, int BM) {
  int m = blockIdx.x;
  if (m >= BM) return;
  int t = threadIdx.x;
  __shared__ float row[EMBED];
  row[t] = ldf<BF>(value, (size_t)m * EMBED + t);
  __syncthreads();
  float acc = ldf<BF>(b_v, t);
#pragma unroll 8
  for (int e = 0; e < EMBED; ++e)
    acc = fmaf(row[e], ldf<BF>(W_v, (size_t)e * EMBED + t), acc);
  if (sizeof(VT) == 2) ((bf16*)v)[(size_t)m * EMBED + t] = __float2bfloat16(acc);
  else                 ((float*)v)[(size_t)m * EMBED + t] = acc;
}

template<class VT>
__global__ __launch_bounds__(256)
void k_value_proj(const void* value, const void* W_v, const void* b_v,
                  VT* v, int BM, const int* flag) {
  if (*flag) vproj_body<true,  VT>(value, W_v, b_v, v, BM);
  else       vproj_body<false, VT>(value, W_v, b_v, v, BM);
}

// ---------------------------------------------------------------------------
extern "C" void kernel_launch(void* const* d_in, const int* in_sizes, int n_in,
                              void* d_out, int out_size, void* d_ws, size_t ws_size,
                              hipStream_t stream) {
  const void* query      = d_in[0];
  const void* value      = d_in[2];
  const void* ref_points = d_in[3];
  const void* W_off  = d_in[6];
  const void* b_off  = d_in[7];
  const void* W_attn = d_in[8];
  const void* b_attn = d_in[9];
  const void* W_v    = d_in[10];
  const void* b_v    = d_in[11];

  const int BN = in_sizes[0] / EMBED;   // 20000
  const int BM = in_sizes[2] / EMBED;   // 43520
  const int N  = BN / BATCH;

  int*  flag    = (int*)d_ws;
  char* ws_base = (char*)d_ws + 256;

  k_detect<<<1, 256, 0, stream>>>((const unsigned short*)query, flag);

  const size_t need_f32 = 256 + (size_t)BM * EMBED * sizeof(float);
  if (ws_size >= need_f32) {
    float* ws_v = (float*)ws_base;
    // <<< the one change vs R2: 8-row LDS-staged GEMV instead of 1-row/block >>>
    k_vgemv8<<<(BM + 7) / 8, 256, 0, stream>>>(value, W_v, b_v, ws_v, BM, flag);
    k_fused<float><<<BN, 256, 0, stream>>>(query, ref_points, W_off, b_off,
                                           W_attn, b_attn, ws_v, d_out, N, BN, flag);
  } else {
    bf16* ws_v = (bf16*)ws_base;
    k_value_proj<bf16><<<BM, 256, 0, stream>>>(value, W_v, b_v, ws_v, BM, flag);
    k_fused<bf16><<<BN, 256, 0, stream>>>(query, ref_points, W_off, b_off,
                                          W_attn, b_attn, ws_v, d_out, N, BN, flag);
  }
}

// Round 7
// 544.864 us; speedup vs baseline: 1.5585x; 1.1303x over previous
//
#include <hip/hip_runtime.h>
#include <hip/hip_bf16.h>

// DeformableAttention3D — MI355X (gfx950)
// R7 = R6 (passing) + ONE new edge: off = query@W_off+b_off via the SAME
// proven k_vgemv8 kernel; k_fused loads s_off from ws instead of computing.
#define EMBED    256
#define HEADS    8
#define LEVELS   4
#define POINTS   4
#define BATCH    2
#define M_TOT    21760   // 128*128 + 64*64 + 32*32 + 16*16

typedef __hip_bfloat16 bf16;
typedef __attribute__((ext_vector_type(8))) short short8;

__device__ __constant__ int c_H[LEVELS]  = {128, 64, 32, 16};
__device__ __constant__ int c_St[LEVELS] = {0, 16384, 20480, 21504};

template<bool BF>
__device__ __forceinline__ float ldf(const void* p, size_t i) {
  if (BF) return __bfloat162float(((const bf16*)p)[i]);
  else    return ((const float*)p)[i];
}
__device__ __forceinline__ float vt2f(float x) { return x; }
__device__ __forceinline__ float vt2f(bf16 x)  { return __bfloat162float(x); }

// ---------------------------------------------------------------------------
// Dtype detector (flag=1 -> buffers bf16, flag=0 -> f32). Verbatim R2/R6.
// ---------------------------------------------------------------------------
__global__ __launch_bounds__(256)
void k_detect(const unsigned short* __restrict__ q16, int* __restrict__ flag) {
  __shared__ int cnt;
  if (threadIdx.x == 0) cnt = 0;
  __syncthreads();
  int c = 0;
  for (int i = threadIdx.x; i < 8192; i += 256) {
    unsigned short v = q16[i];
    if ((v & 0x7F80u) == 0x7F80u) ++c;   // bf16 Inf/NaN pattern
  }
  if (c) atomicAdd(&cnt, c);
  __syncthreads();
  if (threadIdx.x == 0) flag[0] = (cnt == 0) ? 1 : 0;
}

// ---------------------------------------------------------------------------
// PROVEN (R6): 8-rows-per-block LDS-staged GEMV, N = 256 columns fixed.
// C[M x 256] = A[M x 256] @ W[256 x 256] + bias, f32 out.
// Used for BOTH value->v and (new this round) query->off.
// ---------------------------------------------------------------------------
template<bool BF>
__device__ void vgemv8_body(const void* __restrict__ A, const void* __restrict__ W,
                            const void* __restrict__ bias, float* __restrict__ C,
                            int M) {
  const int t  = threadIdx.x;            // 256 threads
  const int r0 = blockIdx.x * 8;
  if (r0 >= M) return;

  __shared__ float rowA[8][EMBED];
  {
    int r  = t >> 5;                     // 0..7
    int rr = min(r0 + r, M - 1);         // clamp reads; stores guarded
    int c0 = (t & 31) * 8;               // 0..248
    if (BF) {
      const bf16* ap = (const bf16*)A + (size_t)rr * EMBED + c0;
      short8 a = *(const short8*)ap;
#pragma unroll
      for (int j = 0; j < 8; ++j) {
        short s = a[j];
        bf16 hb = *reinterpret_cast<bf16*>(&s);
        rowA[r][c0 + j] = __bfloat162float(hb);
      }
    } else {
      const float* ap = (const float*)A + (size_t)rr * EMBED + c0;
#pragma unroll
      for (int j = 0; j < 8; ++j) rowA[r][c0 + j] = ap[j];
    }
  }
  __syncthreads();

  const int n = t;                        // column, N = 256 fixed
  const float b = ldf<BF>(bias, n);
  float acc[8];
#pragma unroll
  for (int r = 0; r < 8; ++r) acc[r] = b;
#pragma unroll 4
  for (int k = 0; k < EMBED; ++k) {
    float w = ldf<BF>(W, (size_t)k * EMBED + n);
#pragma unroll
    for (int r = 0; r < 8; ++r) acc[r] = fmaf(rowA[r][k], w, acc[r]);
  }
#pragma unroll
  for (int r = 0; r < 8; ++r)
    if (r0 + r < M) C[(size_t)(r0 + r) * EMBED + n] = acc[r];
}

__global__ __launch_bounds__(256)
void k_vgemv8(const void* A, const void* W, const void* bias, float* C,
              int M, const int* flag) {
  if (*flag) vgemv8_body<true >(A, W, bias, C, M);
  else       vgemv8_body<false>(A, W, bias, C, M);
}

// ---------------------------------------------------------------------------
// R6's k_fused with ONE change: s_off loaded from precomputed ws_off instead
// of the in-kernel W_off GEMV. Attn GEMV + softmax + sampling VERBATIM.
// ---------------------------------------------------------------------------
template<bool BF, class VT>
__device__ void fused_body(const void* __restrict__ query,
                           const void* __restrict__ ref_points,
                           const float* __restrict__ off_pre,
                           const void* __restrict__ W_attn,
                           const void* __restrict__ b_attn,
                           const VT* __restrict__ v,
                           void* __restrict__ out, int N, int BN) {
  int q = blockIdx.x;
  if (q >= BN) return;
  int b = q / N;
  int t = threadIdx.x;

  __shared__ float row[EMBED];
  __shared__ float s_off[EMBED];
  __shared__ float s_aw[HEADS * LEVELS * POINTS];
  __shared__ float s_rp[2];

  row[t] = ldf<BF>(query, (size_t)q * EMBED + t);
  if (t < 2) s_rp[t] = ldf<BF>(ref_points, (size_t)q * 2 + t);
  __syncthreads();

  // <<< the one change vs R6: load precomputed offsets >>>
  s_off[t] = off_pre[(size_t)q * EMBED + t];

  if (t < 128) {
    float acc = ldf<BF>(b_attn, t);
#pragma unroll 8
    for (int e = 0; e < EMBED; ++e)
      acc = fmaf(row[e], ldf<BF>(W_attn, (size_t)e * 128 + t), acc);
    s_aw[t] = acc;
  }
  __syncthreads();

  float aval = 0.f;
  if (t < 128) {
    int base = t & ~15;
    float mx = -1e30f;
#pragma unroll
    for (int i = 0; i < 16; ++i) mx = fmaxf(mx, s_aw[base + i]);
    float sum = 0.f;
#pragma unroll
    for (int i = 0; i < 16; ++i) sum += expf(s_aw[base + i] - mx);
    aval = expf(s_aw[t] - mx) / sum;
  }
  __syncthreads();
  if (t < 128) s_aw[t] = aval;
  __syncthreads();

  int h = t >> 5;
  const VT* vb = v + (size_t)b * M_TOT * EMBED;
  float o = 0.f;
#pragma unroll
  for (int l = 0; l < LEVELS; ++l) {
    const int Hl = c_H[l], Wl = c_H[l];
    const VT* vl = vb + (size_t)c_St[l] * EMBED;
    const float fW = (float)Wl, fH = (float)Hl;
#pragma unroll
    for (int p = 0; p < POINTS; ++p) {
      int oi = ((h * LEVELS + l) * POINTS + p) << 1;
      float x = (s_rp[0] + s_off[oi]     / fW) * fW - 0.5f;
      float y = (s_rp[1] + s_off[oi + 1] / fH) * fH - 0.5f;
      float x0f = floorf(x), y0f = floorf(y);
      float lx = x - x0f, ly = y - y0f;
      int x0 = (int)x0f, y0 = (int)y0f;
      float wa = s_aw[(h * LEVELS + l) * POINTS + p];
      float cw[4] = {(1.f - lx) * (1.f - ly), lx * (1.f - ly),
                     (1.f - lx) * ly,         lx * ly};
      const int dxs[4] = {0, 1, 0, 1};
      const int dys[4] = {0, 0, 1, 1};
#pragma unroll
      for (int cidx = 0; cidx < 4; ++cidx) {
        int xi = x0 + dxs[cidx];
        int yi = y0 + dys[cidx];
        bool valid = (xi >= 0) & (xi < Wl) & (yi >= 0) & (yi < Hl);
        int xc = min(max(xi, 0), Wl - 1);
        int yc = min(max(yi, 0), Hl - 1);
        float g = vt2f(vl[(size_t)(yc * Wl + xc) * EMBED + t]);
        o += (valid ? wa * cw[cidx] : 0.f) * g;
      }
    }
  }
  if (BF) ((bf16*)out)[(size_t)q * EMBED + t] = __float2bfloat16(o);
  else    ((float*)out)[(size_t)q * EMBED + t] = o;
}

template<class VT>
__global__ __launch_bounds__(256)
void k_fused(const void* query, const void* ref_points, const float* off_pre,
             const void* W_attn, const void* b_attn,
             const VT* v, void* out, int N, int BN, const int* flag) {
  if (*flag) fused_body<true,  VT>(query, ref_points, off_pre, W_attn, b_attn, v, out, N, BN);
  else       fused_body<false, VT>(query, ref_points, off_pre, W_attn, b_attn, v, out, N, BN);
}

// ---------------------------------------------------------------------------
// Fallback path (ws too small): R2/R6's bf16 fused path, fully self-contained.
// ---------------------------------------------------------------------------
template<bool BF, class VT>
__device__ void vproj_body(const void* __restrict__ value,
                           const void* __restrict__ W_v,
                           const void* __restrict__ b_v,
                           VT* __restrict__ v, int BM) {
  int m = blockIdx.x;
  if (m >= BM) return;
  int t = threadIdx.x;
  __shared__ float row[EMBED];
  row[t] = ldf<BF>(value, (size_t)m * EMBED + t);
  __syncthreads();
  float acc = ldf<BF>(b_v, t);
#pragma unroll 8
  for (int e = 0; e < EMBED; ++e)
    acc = fmaf(row[e], ldf<BF>(W_v, (size_t)e * EMBED + t), acc);
  if (sizeof(VT) == 2) ((bf16*)v)[(size_t)m * EMBED + t] = __float2bfloat16(acc);
  else                 ((float*)v)[(size_t)m * EMBED + t] = acc;
}

template<class VT>
__global__ __launch_bounds__(256)
void k_value_proj(const void* value, const void* W_v, const void* b_v,
                  VT* v, int BM, const int* flag) {
  if (*flag) vproj_body<true,  VT>(value, W_v, b_v, v, BM);
  else       vproj_body<false, VT>(value, W_v, b_v, v, BM);
}

template<bool BF, class VT>
__device__ void fusedfb_body(const void* __restrict__ query,
                             const void* __restrict__ ref_points,
                             const void* __restrict__ W_off,
                             const void* __restrict__ b_off,
                             const void* __restrict__ W_attn,
                             const void* __restrict__ b_attn,
                             const VT* __restrict__ v,
                             void* __restrict__ out, int N, int BN) {
  int q = blockIdx.x;
  if (q >= BN) return;
  int b = q / N;
  int t = threadIdx.x;

  __shared__ float row[EMBED];
  __shared__ float s_off[EMBED];
  __shared__ float s_aw[HEADS * LEVELS * POINTS];
  __shared__ float s_rp[2];

  row[t] = ldf<BF>(query, (size_t)q * EMBED + t);
  if (t < 2) s_rp[t] = ldf<BF>(ref_points, (size_t)q * 2 + t);
  __syncthreads();

  {
    float acc = ldf<BF>(b_off, t);
#pragma unroll 8
    for (int e = 0; e < EMBED; ++e)
      acc = fmaf(row[e], ldf<BF>(W_off, (size_t)e * EMBED + t), acc);
    s_off[t] = acc;
  }
  if (t < 128) {
    float acc = ldf<BF>(b_attn, t);
#pragma unroll 8
    for (int e = 0; e < EMBED; ++e)
      acc = fmaf(row[e], ldf<BF>(W_attn, (size_t)e * 128 + t), acc);
    s_aw[t] = acc;
  }
  __syncthreads();

  float aval = 0.f;
  if (t < 128) {
    int base = t & ~15;
    float mx = -1e30f;
#pragma unroll
    for (int i = 0; i < 16; ++i) mx = fmaxf(mx, s_aw[base + i]);
    float sum = 0.f;
#pragma unroll
    for (int i = 0; i < 16; ++i) sum += expf(s_aw[base + i] - mx);
    aval = expf(s_aw[t] - mx) / sum;
  }
  __syncthreads();
  if (t < 128) s_aw[t] = aval;
  __syncthreads();

  int h = t >> 5;
  const VT* vb = v + (size_t)b * M_TOT * EMBED;
  float o = 0.f;
#pragma unroll
  for (int l = 0; l < LEVELS; ++l) {
    const int Hl = c_H[l], Wl = c_H[l];
    const VT* vl = vb + (size_t)c_St[l] * EMBED;
    const float fW = (float)Wl, fH = (float)Hl;
#pragma unroll
    for (int p = 0; p < POINTS; ++p) {
      int oi = ((h * LEVELS + l) * POINTS + p) << 1;
      float x = (s_rp[0] + s_off[oi]     / fW) * fW - 0.5f;
      float y = (s_rp[1] + s_off[oi + 1] / fH) * fH - 0.5f;
      float x0f = floorf(x), y0f = floorf(y);
      float lx = x - x0f, ly = y - y0f;
      int x0 = (int)x0f, y0 = (int)y0f;
      float wa = s_aw[(h * LEVELS + l) * POINTS + p];
      float cw[4] = {(1.f - lx) * (1.f - ly), lx * (1.f - ly),
                     (1.f - lx) * ly,         lx * ly};
      const int dxs[4] = {0, 1, 0, 1};
      const int dys[4] = {0, 0, 1, 1};
#pragma unroll
      for (int cidx = 0; cidx < 4; ++cidx) {
        int xi = x0 + dxs[cidx];
        int yi = y0 + dys[cidx];
        bool valid = (xi >= 0) & (xi < Wl) & (yi >= 0) & (yi < Hl);
        int xc = min(max(xi, 0), Wl - 1);
        int yc = min(max(yi, 0), Hl - 1);
        float g = vt2f(vl[(size_t)(yc * Wl + xc) * EMBED + t]);
        o += (valid ? wa * cw[cidx] : 0.f) * g;
      }
    }
  }
  if (BF) ((bf16*)out)[(size_t)q * EMBED + t] = __float2bfloat16(o);
  else    ((float*)out)[(size_t)q * EMBED + t] = o;
}

template<class VT>
__global__ __launch_bounds__(256)
void k_fused_fb(const void* query, const void* ref_points,
                const void* W_off, const void* b_off,
                const void* W_attn, const void* b_attn,
                const VT* v, void* out, int N, int BN, const int* flag) {
  if (*flag) fusedfb_body<true,  VT>(query, ref_points, W_off, b_off, W_attn, b_attn, v, out, N, BN);
  else       fusedfb_body<false, VT>(query, ref_points, W_off, b_off, W_attn, b_attn, v, out, N, BN);
}

// ---------------------------------------------------------------------------
extern "C" void kernel_launch(void* const* d_in, const int* in_sizes, int n_in,
                              void* d_out, int out_size, void* d_ws, size_t ws_size,
                              hipStream_t stream) {
  const void* query      = d_in[0];
  const void* value      = d_in[2];
  const void* ref_points = d_in[3];
  const void* W_off  = d_in[6];
  const void* b_off  = d_in[7];
  const void* W_attn = d_in[8];
  const void* b_attn = d_in[9];
  const void* W_v    = d_in[10];
  const void* b_v    = d_in[11];

  const int BN = in_sizes[0] / EMBED;   // 20000
  const int BM = in_sizes[2] / EMBED;   // 43520
  const int N  = BN / BATCH;

  int*  flag    = (int*)d_ws;
  char* ws_base = (char*)d_ws + 256;

  k_detect<<<1, 256, 0, stream>>>((const unsigned short*)query, flag);

  const size_t need = 256 + (size_t)BM * EMBED * sizeof(float)
                          + (size_t)BN * EMBED * sizeof(float);
  if (ws_size >= need) {
    float* ws_v   = (float*)ws_base;
    float* ws_off = ws_v + (size_t)BM * EMBED;
    k_vgemv8<<<(BM + 7) / 8, 256, 0, stream>>>(value, W_v, b_v, ws_v, BM, flag);
    k_vgemv8<<<(BN + 7) / 8, 256, 0, stream>>>(query, W_off, b_off, ws_off, BN, flag);
    k_fused<float><<<BN, 256, 0, stream>>>(query, ref_points, ws_off,
                                           W_attn, b_attn, ws_v, d_out, N, BN, flag);
  } else {
    bf16* ws_v = (bf16*)ws_base;
    k_value_proj<bf16><<<BM, 256, 0, stream>>>(value, W_v, b_v, ws_v, BM, flag);
    k_fused_fb<bf16><<<BN, 256, 0, stream>>>(query, ref_points, W_off, b_off,
                                             W_attn, b_attn, ws_v, d_out, N, BN, flag);
  }
}